// Round 2
// baseline (1555.398 us; speedup 1.0000x reference)
//
#include <hip/hip_runtime.h>

typedef unsigned short u16;
typedef unsigned int   u32;

#define NN  100000
#define EE  3200000
#define ETOT 3300000   // EE + NN self-loops
#define FIN 512
#define NB_SCAN 98     // ceil(NN/1024)

__device__ __forceinline__ float bf2f(u16 u){ return __uint_as_float(((u32)u) << 16); }
__device__ __forceinline__ u16 f2bf(float f){
  u32 u = __float_as_uint(f);
  u += 0x7fffu + ((u >> 16) & 1u);       // round-to-nearest-even
  return (u16)(u >> 16);
}

__global__ void k_zero(int* p, int n){
  int i = blockIdx.x*blockDim.x + threadIdx.x;
  if (i < n) p[i] = 0;
}

__global__ void k_hist(const int* __restrict__ ei, int* __restrict__ cnt){
  int e = blockIdx.x*blockDim.x + threadIdx.x;
  if (e >= ETOT) return;
  int d = (e < EE) ? ei[EE + e] : (e - EE);
  atomicAdd(&cnt[d], 1);
}

__global__ void k_scan_a(const int* __restrict__ cnt, int* __restrict__ bsum){
  __shared__ int sd[1024];
  int i = blockIdx.x*1024 + threadIdx.x;
  sd[threadIdx.x] = (i < NN) ? cnt[i] : 0;
  __syncthreads();
  for (int o = 512; o > 0; o >>= 1){
    if (threadIdx.x < o) sd[threadIdx.x] += sd[threadIdx.x + o];
    __syncthreads();
  }
  if (threadIdx.x == 0) bsum[blockIdx.x] = sd[0];
}

__global__ void k_scan_b(int* bsum){
  __shared__ int sd[128];
  int t = threadIdx.x;
  int v = (t < NB_SCAN) ? bsum[t] : 0;
  sd[t] = v; __syncthreads();
  for (int o = 1; o < 128; o <<= 1){
    int x = (t >= o) ? sd[t - o] : 0;
    __syncthreads();
    sd[t] += x;
    __syncthreads();
  }
  if (t < NB_SCAN) bsum[t] = sd[t] - v;   // exclusive
}

__global__ void k_scan_c(int* __restrict__ cnt, const int* __restrict__ bsum,
                         int* __restrict__ indptr){
  __shared__ int sd[1024];
  int t = threadIdx.x;
  int i = blockIdx.x*1024 + t;
  int v = (i < NN) ? cnt[i] : 0;
  sd[t] = v; __syncthreads();
  for (int o = 1; o < 1024; o <<= 1){
    int x = (t >= o) ? sd[t - o] : 0;
    __syncthreads();
    sd[t] += x;
    __syncthreads();
  }
  int excl = sd[t] - v + bsum[blockIdx.x];
  if (i < NN){ indptr[i] = excl; cnt[i] = excl; }   // cnt becomes the fill cursor
  if (i == 0) indptr[NN] = ETOT;
}

__global__ void k_fill(const int* __restrict__ ei, int* __restrict__ cursor,
                       int* __restrict__ srcs){
  int e = blockIdx.x*blockDim.x + threadIdx.x;
  if (e >= ETOT) return;
  int s, d;
  if (e < EE){ s = ei[e]; d = ei[EE + e]; } else { s = e - EE; d = s; }
  int pos = atomicAdd(&cursor[d], 1);
  srcs[pos] = s;
}

__global__ void k_transpose(const float* __restrict__ W1, float* __restrict__ WT){
  int i = blockIdx.x*blockDim.x + threadIdx.x;   // 0..16383
  if (i >= FIN*32) return;
  int k = i >> 5, c = i & 31;
  WT[c*FIN + k] = W1[i];
}

// x[100k,512](f32) @ W1[512,32] -> xp1 (bf16), plus per-head attention scalars in f32.
// 256 threads: 8 nodes x 32 cols per block. x tile in LDS (broadcast reads),
// W^T columns via L1/L2.
__global__ void __launch_bounds__(256) k_gemm1(
    const float* __restrict__ x, const float* __restrict__ WT,
    const float* __restrict__ attS, const float* __restrict__ attD,
    u16* __restrict__ xp1, float* __restrict__ as1, float* __restrict__ ad1){
  __shared__ float xs[8 * FIN];   // 16 KiB
  int tid = threadIdx.x;
  int nb = blockIdx.x * 8;
  const float4* xg = (const float4*)(x + (size_t)nb * FIN);
  float4* xs4 = (float4*)xs;
  #pragma unroll
  for (int i = 0; i < 4; i++) xs4[tid + 256*i] = xg[tid + 256*i];
  __syncthreads();
  int nl = tid >> 5, col = tid & 31;
  const float* xl = xs + nl * FIN;
  const float* wc = WT + col * FIN;
  float acc = 0.f;
  #pragma unroll 8
  for (int k = 0; k < FIN; k += 4){
    float4 wv = *(const float4*)(wc + k);
    float4 xv = *(const float4*)(xl + k);
    acc = fmaf(xv.x, wv.x, acc);
    acc = fmaf(xv.y, wv.y, acc);
    acc = fmaf(xv.z, wv.z, acc);
    acc = fmaf(xv.w, wv.w, acc);
  }
  int n = nb + nl;
  float ps = acc * attS[col];
  float pd = acc * attD[col];
  ps += __shfl_xor(ps, 1); ps += __shfl_xor(ps, 2); ps += __shfl_xor(ps, 4);
  pd += __shfl_xor(pd, 1); pd += __shfl_xor(pd, 2); pd += __shfl_xor(pd, 4);
  xp1[(size_t)n*32 + col] = f2bf(acc);
  if ((col & 7) == 0){
    as1[n*4 + (col >> 3)] = ps;
    ad1[n*4 + (col >> 3)] = pd;
  }
}

// Layer-1 aggregation: one wave per dst. Lane = (edge-pair p, head h, chan c).
// Unnormalized softmax (shift-invariant; logits ~ +-3 so exp is safe in f32);
// self-loop guarantees den>0.
__global__ void __launch_bounds__(256) k_agg1(
    const int* __restrict__ indptr, const int* __restrict__ srcs,
    const u16* __restrict__ xp1, const float* __restrict__ as1,
    const float* __restrict__ ad1, const float* __restrict__ b1,
    u16* __restrict__ hfeat){
  int wid = (blockIdx.x * 256 + threadIdx.x) >> 6;
  if (wid >= NN) return;
  int lane = threadIdx.x & 63;
  int p = lane >> 5, hc = lane & 31, h = hc >> 3;
  int beg = indptr[wid], end = indptr[wid + 1];
  float ad = ad1[wid*4 + h];
  float num = 0.f, den = 0.f;
  for (int j = beg + p; j < end; j += 2){
    int s = srcs[j];
    float z = as1[s*4 + h] + ad;
    z = (z >= 0.f) ? z : 0.2f * z;          // leaky_relu 0.2
    float w = __expf(z);
    num = fmaf(w, bf2f(xp1[(size_t)s*32 + hc]), num);
    den += w;
  }
  num += __shfl_xor(num, 32);
  den += __shfl_xor(den, 32);
  if (p == 0){
    float o = num / den + b1[hc];
    o = (o > 0.f) ? o : (__expf(o) - 1.f);  // ELU
    hfeat[(size_t)wid*32 + hc] = f2bf(o);
  }
}

// h[100k,32] @ W2[32,8] + attention scalars for layer 2. One thread per node.
__global__ void k_feat2(const u16* __restrict__ hfeat, const float* __restrict__ W2,
                        const float* __restrict__ attS, const float* __restrict__ attD,
                        float* __restrict__ xp2, float* __restrict__ as2,
                        float* __restrict__ ad2){
  int n = blockIdx.x*blockDim.x + threadIdx.x;
  if (n >= NN) return;
  const u16* hr = hfeat + (size_t)n*32;
  float h[32];
  #pragma unroll
  for (int k = 0; k < 32; k++) h[k] = bf2f(hr[k]);
  float o[8];
  #pragma unroll
  for (int j = 0; j < 8; j++) o[j] = 0.f;
  #pragma unroll
  for (int k = 0; k < 32; k++){
    #pragma unroll
    for (int j = 0; j < 8; j++) o[j] = fmaf(h[k], W2[k*8 + j], o[j]);
  }
  float s = 0.f, d = 0.f;
  #pragma unroll
  for (int j = 0; j < 8; j++){
    xp2[(size_t)n*8 + j] = o[j];
    s = fmaf(o[j], attS[j], s);
    d = fmaf(o[j], attD[j], d);
  }
  as2[n] = s; ad2[n] = d;
}

// Layer-2 aggregation: one wave per dst. Lane = (edge slot p 0..7, chan c 0..7).
__global__ void __launch_bounds__(256) k_agg2(
    const int* __restrict__ indptr, const int* __restrict__ srcs,
    const float* __restrict__ xp2, const float* __restrict__ as2,
    const float* __restrict__ ad2, const float* __restrict__ b2,
    float* __restrict__ out){
  int wid = (blockIdx.x * 256 + threadIdx.x) >> 6;
  if (wid >= NN) return;
  int lane = threadIdx.x & 63;
  int p = lane >> 3, c = lane & 7;
  int beg = indptr[wid], end = indptr[wid + 1];
  float ad = ad2[wid];
  float num = 0.f, den = 0.f;
  for (int j = beg + p; j < end; j += 8){
    int s = srcs[j];
    float z = as2[s] + ad;
    z = (z >= 0.f) ? z : 0.2f * z;
    float w = __expf(z);
    num = fmaf(w, xp2[(size_t)s*8 + c], num);
    den += w;
  }
  num += __shfl_xor(num, 8);  den += __shfl_xor(den, 8);
  num += __shfl_xor(num, 16); den += __shfl_xor(den, 16);
  num += __shfl_xor(num, 32); den += __shfl_xor(den, 32);
  if (p == 0){
    out[(size_t)wid*8 + c] = num / den + b2[c];
  }
}

extern "C" void kernel_launch(void* const* d_in, const int* in_sizes, int n_in,
                              void* d_out, int out_size, void* d_ws, size_t ws_size,
                              hipStream_t stream){
  (void)in_sizes; (void)n_in; (void)out_size; (void)ws_size;
  const float* x   = (const float*)d_in[0];
  const int*   ei  = (const int*)d_in[1];
  const float* W1  = (const float*)d_in[2];
  const float* aS1 = (const float*)d_in[3];
  const float* aD1 = (const float*)d_in[4];
  const float* b1  = (const float*)d_in[5];
  const float* W2  = (const float*)d_in[6];
  const float* aS2 = (const float*)d_in[7];
  const float* aD2 = (const float*)d_in[8];
  const float* b2  = (const float*)d_in[9];
  float* out = (float*)d_out;

  // workspace layout (~35 MB), all 16B-aligned
  char* w = (char*)d_ws;
  int*   cnt    = (int*)w;   w += 400000;            // N ints; reused as fill cursor
  int*   indptr = (int*)w;   w += 400016;            // N+1 ints
  int*   bsum   = (int*)w;   w += 1024;
  int*   srcs   = (int*)w;   w += (size_t)ETOT*4;    // 13.2 MB
  u16*   xp1    = (u16*)w;   w += (size_t)NN*32*2;   // 6.4 MB
  float* as1    = (float*)w; w += (size_t)NN*4*4;
  float* ad1    = (float*)w; w += (size_t)NN*4*4;
  u16*   hfeat  = (u16*)w;   w += (size_t)NN*32*2;
  float* xp2    = (float*)w; w += (size_t)NN*8*4;
  float* as2    = (float*)w; w += (size_t)NN*4;
  float* ad2    = (float*)w; w += (size_t)NN*4;
  float* WT     = (float*)w; w += 32*512*4;

  k_zero     <<<(NN+255)/256,   256, 0, stream>>>(cnt, NN);
  k_hist     <<<(ETOT+255)/256, 256, 0, stream>>>(ei, cnt);
  k_scan_a   <<<NB_SCAN, 1024, 0, stream>>>(cnt, bsum);
  k_scan_b   <<<1, 128, 0, stream>>>(bsum);
  k_scan_c   <<<NB_SCAN, 1024, 0, stream>>>(cnt, bsum, indptr);
  k_fill     <<<(ETOT+255)/256, 256, 0, stream>>>(ei, cnt, srcs);
  k_transpose<<<64, 256, 0, stream>>>(W1, WT);
  k_gemm1    <<<NN/8, 256, 0, stream>>>(x, WT, aS1, aD1, xp1, as1, ad1);
  k_agg1     <<<NN/4, 256, 0, stream>>>(indptr, srcs, xp1, as1, ad1, b1, hfeat);
  k_feat2    <<<(NN+255)/256, 256, 0, stream>>>(hfeat, W2, aS2, aD2, xp2, as2, ad2);
  k_agg2     <<<NN/4, 256, 0, stream>>>(indptr, srcs, xp2, as2, ad2, b2, out);
}

// Round 3
// 939.552 us; speedup vs baseline: 1.6555x; 1.6555x over previous
//
#include <hip/hip_runtime.h>

typedef unsigned short u16;
typedef unsigned int   u32;

#define NN  100000
#define EE  3200000
#define ETOT 3300000   // EE + NN self-loops
#define FIN 512
#define NB_SCAN 98     // ceil(NN/1024)

typedef __attribute__((ext_vector_type(8))) short bfx8;   // 8 bf16 (4 VGPRs)
typedef __attribute__((ext_vector_type(4))) float f32x4;  // MFMA C/D

__device__ __forceinline__ float bf2f(u16 u){ return __uint_as_float(((u32)u) << 16); }
__device__ __forceinline__ u16 f2bf(float f){
  u32 u = __float_as_uint(f);
  u += 0x7fffu + ((u >> 16) & 1u);       // round-to-nearest-even
  return (u16)(u >> 16);
}
__device__ __forceinline__ u32 pack2(float a, float b){
  return ((u32)f2bf(b) << 16) | (u32)f2bf(a);
}

__global__ void k_zero(int* p, int n){
  int i = blockIdx.x*blockDim.x + threadIdx.x;
  if (i < n) p[i] = 0;
}

__global__ void k_hist(const int* __restrict__ ei, int* __restrict__ cnt){
  int e = blockIdx.x*blockDim.x + threadIdx.x;
  if (e >= ETOT) return;
  int d = (e < EE) ? ei[EE + e] : (e - EE);
  atomicAdd(&cnt[d], 1);
}

__global__ void k_scan_a(const int* __restrict__ cnt, int* __restrict__ bsum){
  __shared__ int sd[1024];
  int i = blockIdx.x*1024 + threadIdx.x;
  sd[threadIdx.x] = (i < NN) ? cnt[i] : 0;
  __syncthreads();
  for (int o = 512; o > 0; o >>= 1){
    if (threadIdx.x < o) sd[threadIdx.x] += sd[threadIdx.x + o];
    __syncthreads();
  }
  if (threadIdx.x == 0) bsum[blockIdx.x] = sd[0];
}

__global__ void k_scan_b(int* bsum){
  __shared__ int sd[128];
  int t = threadIdx.x;
  int v = (t < NB_SCAN) ? bsum[t] : 0;
  sd[t] = v; __syncthreads();
  for (int o = 1; o < 128; o <<= 1){
    int x = (t >= o) ? sd[t - o] : 0;
    __syncthreads();
    sd[t] += x;
    __syncthreads();
  }
  if (t < NB_SCAN) bsum[t] = sd[t] - v;   // exclusive
}

__global__ void k_scan_c(int* __restrict__ cnt, const int* __restrict__ bsum,
                         int* __restrict__ indptr){
  __shared__ int sd[1024];
  int t = threadIdx.x;
  int i = blockIdx.x*1024 + t;
  int v = (i < NN) ? cnt[i] : 0;
  sd[t] = v; __syncthreads();
  for (int o = 1; o < 1024; o <<= 1){
    int x = (t >= o) ? sd[t - o] : 0;
    __syncthreads();
    sd[t] += x;
    __syncthreads();
  }
  int excl = sd[t] - v + bsum[blockIdx.x];
  if (i < NN){ indptr[i] = excl; cnt[i] = excl; }   // cnt becomes the fill cursor
  if (i == 0) indptr[NN] = ETOT;
}

__global__ void k_fill(const int* __restrict__ ei, int* __restrict__ cursor,
                       int* __restrict__ srcs){
  int e = blockIdx.x*blockDim.x + threadIdx.x;
  if (e >= ETOT) return;
  int s, d;
  if (e < EE){ s = ei[e]; d = ei[EE + e]; } else { s = e - EE; d = s; }
  int pos = atomicAdd(&cursor[d], 1);
  srcs[pos] = s;
}

// W1[512,32] f32 -> WTb[col][k] bf16 (32 x 512)
__global__ void k_prep_w(const float* __restrict__ W1, u16* __restrict__ WTb){
  int i = blockIdx.x*blockDim.x + threadIdx.x;   // 0..16383
  if (i >= FIN*32) return;
  int k = i >> 5, c = i & 31;
  WTb[c*FIN + k] = f2bf(W1[i]);
}

// MFMA GEMM: xp1[100k,32] = bf16(x) @ bf16(W1), f32 accumulate.
// Block: 64 nodes x 32 cols, 4 waves (16 rows each, two 16x16 C-tiles).
// x staged f32->bf16 into padded LDS per 128-K chunk; W^T bf16 staged once.
__global__ void __launch_bounds__(256) k_gemm1(
    const float* __restrict__ x, const u16* __restrict__ WTb,
    const float* __restrict__ attS, const float* __restrict__ attD,
    u16* __restrict__ xp1, float* __restrict__ as1, float* __restrict__ ad1){
  __shared__ u16 xs[64 * 136];   // 64 rows x (128 + 8 pad) bf16 = 17408 B
  __shared__ u16 ws[32 * 520];   // 32 cols x (512 + 8 pad) bf16 = 33280 B
  int tid = threadIdx.x;
  int nb  = blockIdx.x * 64;

  // stage W^T bf16 once (coalesced; 128 B/thread)
  {
    int r = tid >> 3, seg = tid & 7;
    const uint4* src = (const uint4*)(WTb + r*FIN + seg*64);
    uint4* dst = (uint4*)(ws + r*520 + seg*64);
    #pragma unroll
    for (int i = 0; i < 8; i++) dst[i] = src[i];
  }

  int sr = tid >> 2, sseg = tid & 3;                 // staging: 4 threads/row
  int rowc = nb + sr; if (rowc >= NN) rowc = NN - 1; // clamp (dup rows, stores guarded)
  const float* xrow = x + (size_t)rowc * FIN;

  int lane = tid & 63, wid = tid >> 6;
  int m = lane & 15, quad = lane >> 4;
  int rowbase = wid * 16;
  const u16* a_base  = xs + (rowbase + m) * 136 + quad * 8;
  const u16* b0_base = ws + m * 520 + quad * 8;
  const u16* b1_base = b0_base + 16 * 520;

  f32x4 acc0 = {0.f, 0.f, 0.f, 0.f};
  f32x4 acc1 = {0.f, 0.f, 0.f, 0.f};

  for (int kc = 0; kc < 4; kc++){
    // stage x chunk: 64 rows x 128 k, convert to bf16
    const float4* g = (const float4*)(xrow + kc*128 + sseg*32);
    #pragma unroll
    for (int i = 0; i < 4; i++){
      float4 f0 = g[2*i], f1 = g[2*i+1];
      uint4 wv;
      wv.x = pack2(f0.x, f0.y); wv.y = pack2(f0.z, f0.w);
      wv.z = pack2(f1.x, f1.y); wv.w = pack2(f1.z, f1.w);
      *(uint4*)(xs + sr*136 + sseg*32 + i*8) = wv;
    }
    __syncthreads();
    #pragma unroll
    for (int ks = 0; ks < 4; ks++){
      bfx8 a  = *(const bfx8*)(a_base + ks*32);
      bfx8 b0 = *(const bfx8*)(b0_base + kc*128 + ks*32);
      bfx8 b1 = *(const bfx8*)(b1_base + kc*128 + ks*32);
      acc0 = __builtin_amdgcn_mfma_f32_16x16x32_bf16(a, b0, acc0, 0, 0, 0);
      acc1 = __builtin_amdgcn_mfma_f32_16x16x32_bf16(a, b1, acc1, 0, 0, 0);
    }
    __syncthreads();
  }

  // epilogue: C/D layout col=lane&15, row=quad*4+reg
  #pragma unroll
  for (int t = 0; t < 2; t++){
    f32x4 acc = t ? acc1 : acc0;
    int colg = t*16 + m;
    float aS = attS[colg], aD = attD[colg];
    #pragma unroll
    for (int r = 0; r < 4; r++){
      int node = nb + rowbase + quad*4 + r;
      float v = acc[r];
      if (node < NN) xp1[(size_t)node*32 + colg] = f2bf(v);
      float ps = v * aS, pd = v * aD;
      ps += __shfl_xor(ps, 1); ps += __shfl_xor(ps, 2); ps += __shfl_xor(ps, 4);
      pd += __shfl_xor(pd, 1); pd += __shfl_xor(pd, 2); pd += __shfl_xor(pd, 4);
      if ((m & 7) == 0 && node < NN){
        as1[node*4 + (colg >> 3)] = ps;
        ad1[node*4 + (colg >> 3)] = pd;
      }
    }
  }
}

// Layer-1 aggregation: one wave per dst. Lane = (edge-pair p, head h, chan c).
// Unnormalized softmax (shift-invariant; logits small so exp is safe in f32);
// self-loop guarantees den>0.
__global__ void __launch_bounds__(256) k_agg1(
    const int* __restrict__ indptr, const int* __restrict__ srcs,
    const u16* __restrict__ xp1, const float* __restrict__ as1,
    const float* __restrict__ ad1, const float* __restrict__ b1,
    u16* __restrict__ hfeat){
  int wid = (blockIdx.x * 256 + threadIdx.x) >> 6;
  if (wid >= NN) return;
  int lane = threadIdx.x & 63;
  int p = lane >> 5, hc = lane & 31, h = hc >> 3;
  int beg = indptr[wid], end = indptr[wid + 1];
  float ad = ad1[wid*4 + h];
  float num = 0.f, den = 0.f;
  for (int j = beg + p; j < end; j += 2){
    int s = srcs[j];
    float z = as1[s*4 + h] + ad;
    z = (z >= 0.f) ? z : 0.2f * z;          // leaky_relu 0.2
    float w = __expf(z);
    num = fmaf(w, bf2f(xp1[(size_t)s*32 + hc]), num);
    den += w;
  }
  num += __shfl_xor(num, 32);
  den += __shfl_xor(den, 32);
  if (p == 0){
    float o = num / den + b1[hc];
    o = (o > 0.f) ? o : (__expf(o) - 1.f);  // ELU
    hfeat[(size_t)wid*32 + hc] = f2bf(o);
  }
}

// h[100k,32] @ W2[32,8] + attention scalars for layer 2. One thread per node.
__global__ void k_feat2(const u16* __restrict__ hfeat, const float* __restrict__ W2,
                        const float* __restrict__ attS, const float* __restrict__ attD,
                        float* __restrict__ xp2, float* __restrict__ as2,
                        float* __restrict__ ad2){
  int n = blockIdx.x*blockDim.x + threadIdx.x;
  if (n >= NN) return;
  const u16* hr = hfeat + (size_t)n*32;
  float h[32];
  #pragma unroll
  for (int k = 0; k < 32; k++) h[k] = bf2f(hr[k]);
  float o[8];
  #pragma unroll
  for (int j = 0; j < 8; j++) o[j] = 0.f;
  #pragma unroll
  for (int k = 0; k < 32; k++){
    #pragma unroll
    for (int j = 0; j < 8; j++) o[j] = fmaf(h[k], W2[k*8 + j], o[j]);
  }
  float s = 0.f, d = 0.f;
  #pragma unroll
  for (int j = 0; j < 8; j++){
    xp2[(size_t)n*8 + j] = o[j];
    s = fmaf(o[j], attS[j], s);
    d = fmaf(o[j], attD[j], d);
  }
  as2[n] = s; ad2[n] = d;
}

// Layer-2 aggregation: one wave per dst. Lane = (edge slot p 0..7, chan c 0..7).
__global__ void __launch_bounds__(256) k_agg2(
    const int* __restrict__ indptr, const int* __restrict__ srcs,
    const float* __restrict__ xp2, const float* __restrict__ as2,
    const float* __restrict__ ad2, const float* __restrict__ b2,
    float* __restrict__ out){
  int wid = (blockIdx.x * 256 + threadIdx.x) >> 6;
  if (wid >= NN) return;
  int lane = threadIdx.x & 63;
  int p = lane >> 3, c = lane & 7;
  int beg = indptr[wid], end = indptr[wid + 1];
  float ad = ad2[wid];
  float num = 0.f, den = 0.f;
  for (int j = beg + p; j < end; j += 8){
    int s = srcs[j];
    float z = as2[s] + ad;
    z = (z >= 0.f) ? z : 0.2f * z;
    float w = __expf(z);
    num = fmaf(w, xp2[(size_t)s*8 + c], num);
    den += w;
  }
  num += __shfl_xor(num, 8);  den += __shfl_xor(den, 8);
  num += __shfl_xor(num, 16); den += __shfl_xor(den, 16);
  num += __shfl_xor(num, 32); den += __shfl_xor(den, 32);
  if (p == 0){
    out[(size_t)wid*8 + c] = num / den + b2[c];
  }
}

extern "C" void kernel_launch(void* const* d_in, const int* in_sizes, int n_in,
                              void* d_out, int out_size, void* d_ws, size_t ws_size,
                              hipStream_t stream){
  (void)in_sizes; (void)n_in; (void)out_size; (void)ws_size;
  const float* x   = (const float*)d_in[0];
  const int*   ei  = (const int*)d_in[1];
  const float* W1  = (const float*)d_in[2];
  const float* aS1 = (const float*)d_in[3];
  const float* aD1 = (const float*)d_in[4];
  const float* b1  = (const float*)d_in[5];
  const float* W2  = (const float*)d_in[6];
  const float* aS2 = (const float*)d_in[7];
  const float* aD2 = (const float*)d_in[8];
  const float* b2  = (const float*)d_in[9];
  float* out = (float*)d_out;

  // workspace layout (~35 MB), all 16B-aligned
  char* w = (char*)d_ws;
  int*   cnt    = (int*)w;   w += 400000;            // N ints; reused as fill cursor
  int*   indptr = (int*)w;   w += 400016;            // N+1 ints
  int*   bsum   = (int*)w;   w += 1024;
  int*   srcs   = (int*)w;   w += (size_t)ETOT*4;    // 13.2 MB
  u16*   xp1    = (u16*)w;   w += (size_t)NN*32*2;   // 6.4 MB
  float* as1    = (float*)w; w += (size_t)NN*4*4;
  float* ad1    = (float*)w; w += (size_t)NN*4*4;
  u16*   hfeat  = (u16*)w;   w += (size_t)NN*32*2;
  float* xp2    = (float*)w; w += (size_t)NN*8*4;
  float* as2    = (float*)w; w += (size_t)NN*4;
  float* ad2    = (float*)w; w += (size_t)NN*4;
  u16*   WTb    = (u16*)w;   w += 32*512*2;

  k_zero   <<<(NN+255)/256,   256, 0, stream>>>(cnt, NN);
  k_hist   <<<(ETOT+255)/256, 256, 0, stream>>>(ei, cnt);
  k_scan_a <<<NB_SCAN, 1024, 0, stream>>>(cnt, bsum);
  k_scan_b <<<1, 128, 0, stream>>>(bsum);
  k_scan_c <<<NB_SCAN, 1024, 0, stream>>>(cnt, bsum, indptr);
  k_fill   <<<(ETOT+255)/256, 256, 0, stream>>>(ei, cnt, srcs);
  k_prep_w <<<64, 256, 0, stream>>>(W1, WTb);
  k_gemm1  <<<(NN+63)/64, 256, 0, stream>>>(x, WTb, aS1, aD1, xp1, as1, ad1);
  k_agg1   <<<NN/4, 256, 0, stream>>>(indptr, srcs, xp1, as1, ad1, b1, hfeat);
  k_feat2  <<<(NN+255)/256, 256, 0, stream>>>(hfeat, W2, aS2, aD2, xp2, as2, ad2);
  k_agg2   <<<NN/4, 256, 0, stream>>>(indptr, srcs, xp2, as2, ad2, b2, out);
}

// Round 4
// 641.934 us; speedup vs baseline: 2.4230x; 1.4636x over previous
//
#include <hip/hip_runtime.h>

typedef unsigned short u16;
typedef unsigned int   u32;

#define NN  100000
#define EE  3200000
#define ETOT 3300000   // EE + NN self-loops
#define FIN 512
#define NBUK 512
#define NPB  196       // nodes per bucket; 512*196 = 100352 >= NN
#define TILE_A 8192    // edges per k_binA block
#define NBLK_A ((ETOT + TILE_A - 1) / TILE_A)   // 403

typedef __attribute__((ext_vector_type(8))) short bfx8;   // 8 bf16 (4 VGPRs)
typedef __attribute__((ext_vector_type(4))) float f32x4;  // MFMA C/D

__device__ __forceinline__ float bf2f(u16 u){ return __uint_as_float(((u32)u) << 16); }
__device__ __forceinline__ u16 f2bf(float f){
  u32 u = __float_as_uint(f);
  u += 0x7fffu + ((u >> 16) & 1u);       // round-to-nearest-even
  return (u16)(u >> 16);
}
__device__ __forceinline__ u32 pack2(float a, float b){
  return ((u32)f2bf(b) << 16) | (u32)f2bf(a);
}

// ---------- CSR build: bucketed two-pass counting sort ----------

// bucket histogram: LDS per-block, flush once (bcnt pre-zeroed by memset)
__global__ void __launch_bounds__(256) k_bcnt(const int* __restrict__ ei,
                                              u32* __restrict__ bcnt){
  __shared__ u32 h[NBUK];
  int t = threadIdx.x;
  h[t] = 0; h[t + 256] = 0;
  __syncthreads();
  int stride = gridDim.x * 256;
  for (int e = blockIdx.x*256 + t; e < ETOT; e += stride){
    int d = (e < EE) ? ei[EE + e] : (e - EE);
    atomicAdd(&h[(u32)d / NPB], 1u);
  }
  __syncthreads();
  u32 v0 = h[t], v1 = h[t + 256];
  if (v0) atomicAdd(&bcnt[t], v0);
  if (v1) atomicAdd(&bcnt[t + 256], v1);
}

// exclusive scan of 512 bucket counts -> bbase[513], gcur; indptr[NN]=ETOT
__global__ void __launch_bounds__(512) k_bscan(const u32* __restrict__ bcnt,
                                               u32* __restrict__ bbase,
                                               u32* __restrict__ gcur,
                                               int* __restrict__ indptr){
  __shared__ u32 sd[512];
  int t = threadIdx.x;
  u32 v = bcnt[t];
  sd[t] = v; __syncthreads();
  for (int o = 1; o < 512; o <<= 1){
    u32 x = (t >= o) ? sd[t - o] : 0;
    __syncthreads();
    sd[t] += x;
    __syncthreads();
  }
  u32 excl = sd[t] - v;
  bbase[t] = excl; gcur[t] = excl;
  if (t == 511) bbase[512] = sd[511];   // == ETOT
  if (t == 0)   indptr[NN] = ETOT;
}

// bin edges into bucket-contiguous regions as packed (dlocal<<17)|src
__global__ void __launch_bounds__(256) k_binA(const int* __restrict__ ei,
                                              u32* __restrict__ gcur,
                                              u32* __restrict__ buk){
  __shared__ u32 hcnt[NBUK];
  __shared__ u32 hbase[NBUK];
  int t = threadIdx.x;
  hcnt[t] = 0; hcnt[t + 256] = 0;
  __syncthreads();
  int e0 = blockIdx.x * TILE_A;
  u32 pk[32], meta[32];
  #pragma unroll
  for (int i = 0; i < 32; i++){
    int e = e0 + i*256 + t;
    if (e < ETOT){
      int s, d;
      if (e < EE){ s = ei[e]; d = ei[EE + e]; } else { s = e - EE; d = s; }
      u32 b = (u32)d / NPB;
      pk[i] = ((u32)(d - (int)b*NPB) << 17) | (u32)s;
      u32 r = atomicAdd(&hcnt[b], 1u);
      meta[i] = (b << 13) | r;          // r < 8192
    } else meta[i] = 0xFFFFFFFFu;
  }
  __syncthreads();
  for (int q = t; q < NBUK; q += 256){
    u32 c = hcnt[q];
    if (c) hbase[q] = atomicAdd(&gcur[q], c);
  }
  __syncthreads();
  #pragma unroll
  for (int i = 0; i < 32; i++){
    if (meta[i] != 0xFFFFFFFFu){
      u32 b = meta[i] >> 13, r = meta[i] & 8191u;
      buk[hbase[b] + r] = pk[i];
    }
  }
}

// per-bucket: count dsts, LDS scan -> indptr + cursors, scatter srcs (L2-local)
__global__ void __launch_bounds__(256) k_scatterB(const u32* __restrict__ bbase,
                                                  const u32* __restrict__ buk,
                                                  int* __restrict__ indptr,
                                                  int* __restrict__ srcs){
  __shared__ u32 dcnt[NPB + 1];
  __shared__ u32 cur[NPB];
  int b = blockIdx.x, t = threadIdx.x;
  u32 lo = bbase[b], hi = bbase[b + 1];
  if (t < NPB + 1) dcnt[t] = 0;
  __syncthreads();
  for (u32 j = lo + t; j < hi; j += 256)
    atomicAdd(&dcnt[(buk[j] >> 17) + 1], 1u);
  __syncthreads();
  // inclusive scan over dcnt[0..NPB] -> dcnt[k] = exclusive prefix for dlocal=k
  for (int o = 1; o < 256; o <<= 1){
    u32 x = 0;
    if (t < NPB + 1 && t >= o) x = dcnt[t - o];
    __syncthreads();
    if (t < NPB + 1 && t >= o) dcnt[t] += x;
    __syncthreads();
  }
  if (t < NPB){
    u32 off = lo + dcnt[t];
    cur[t] = off;
    int node = b * NPB + t;
    if (node < NN) indptr[node] = (int)off;
  }
  __syncthreads();
  for (u32 j = lo + t; j < hi; j += 256){
    u32 p = buk[j];
    u32 pos = atomicAdd(&cur[p >> 17], 1u);
    srcs[pos] = (int)(p & 0x1FFFFu);
  }
}

// ---------- compute kernels (unchanged from round 3) ----------

// W1[512,32] f32 -> WTb[col][k] bf16 (32 x 512)
__global__ void k_prep_w(const float* __restrict__ W1, u16* __restrict__ WTb){
  int i = blockIdx.x*blockDim.x + threadIdx.x;   // 0..16383
  if (i >= FIN*32) return;
  int k = i >> 5, c = i & 31;
  WTb[c*FIN + k] = f2bf(W1[i]);
}

// MFMA GEMM: xp1[100k,32] = bf16(x) @ bf16(W1), f32 accumulate.
__global__ void __launch_bounds__(256) k_gemm1(
    const float* __restrict__ x, const u16* __restrict__ WTb,
    const float* __restrict__ attS, const float* __restrict__ attD,
    u16* __restrict__ xp1, float* __restrict__ as1, float* __restrict__ ad1){
  __shared__ u16 xs[64 * 136];   // 64 rows x (128 + 8 pad) bf16
  __shared__ u16 ws[32 * 520];   // 32 cols x (512 + 8 pad) bf16
  int tid = threadIdx.x;
  int nb  = blockIdx.x * 64;

  {
    int r = tid >> 3, seg = tid & 7;
    const uint4* src = (const uint4*)(WTb + r*FIN + seg*64);
    uint4* dst = (uint4*)(ws + r*520 + seg*64);
    #pragma unroll
    for (int i = 0; i < 8; i++) dst[i] = src[i];
  }

  int sr = tid >> 2, sseg = tid & 3;
  int rowc = nb + sr; if (rowc >= NN) rowc = NN - 1;
  const float* xrow = x + (size_t)rowc * FIN;

  int lane = tid & 63, wid = tid >> 6;
  int m = lane & 15, quad = lane >> 4;
  int rowbase = wid * 16;
  const u16* a_base  = xs + (rowbase + m) * 136 + quad * 8;
  const u16* b0_base = ws + m * 520 + quad * 8;
  const u16* b1_base = b0_base + 16 * 520;

  f32x4 acc0 = {0.f, 0.f, 0.f, 0.f};
  f32x4 acc1 = {0.f, 0.f, 0.f, 0.f};

  for (int kc = 0; kc < 4; kc++){
    const float4* g = (const float4*)(xrow + kc*128 + sseg*32);
    #pragma unroll
    for (int i = 0; i < 4; i++){
      float4 f0 = g[2*i], f1 = g[2*i+1];
      uint4 wv;
      wv.x = pack2(f0.x, f0.y); wv.y = pack2(f0.z, f0.w);
      wv.z = pack2(f1.x, f1.y); wv.w = pack2(f1.z, f1.w);
      *(uint4*)(xs + sr*136 + sseg*32 + i*8) = wv;
    }
    __syncthreads();
    #pragma unroll
    for (int ks = 0; ks < 4; ks++){
      bfx8 a  = *(const bfx8*)(a_base + ks*32);
      bfx8 b0 = *(const bfx8*)(b0_base + kc*128 + ks*32);
      bfx8 b1 = *(const bfx8*)(b1_base + kc*128 + ks*32);
      acc0 = __builtin_amdgcn_mfma_f32_16x16x32_bf16(a, b0, acc0, 0, 0, 0);
      acc1 = __builtin_amdgcn_mfma_f32_16x16x32_bf16(a, b1, acc1, 0, 0, 0);
    }
    __syncthreads();
  }

  #pragma unroll
  for (int t = 0; t < 2; t++){
    f32x4 acc = t ? acc1 : acc0;
    int colg = t*16 + m;
    float aS = attS[colg], aD = attD[colg];
    #pragma unroll
    for (int r = 0; r < 4; r++){
      int node = nb + rowbase + quad*4 + r;
      float v = acc[r];
      if (node < NN) xp1[(size_t)node*32 + colg] = f2bf(v);
      float ps = v * aS, pd = v * aD;
      ps += __shfl_xor(ps, 1); ps += __shfl_xor(ps, 2); ps += __shfl_xor(ps, 4);
      pd += __shfl_xor(pd, 1); pd += __shfl_xor(pd, 2); pd += __shfl_xor(pd, 4);
      if ((m & 7) == 0 && node < NN){
        as1[node*4 + (colg >> 3)] = ps;
        ad1[node*4 + (colg >> 3)] = pd;
      }
    }
  }
}

// Layer-1 aggregation: one wave per dst.
__global__ void __launch_bounds__(256) k_agg1(
    const int* __restrict__ indptr, const int* __restrict__ srcs,
    const u16* __restrict__ xp1, const float* __restrict__ as1,
    const float* __restrict__ ad1, const float* __restrict__ b1,
    u16* __restrict__ hfeat){
  int wid = (blockIdx.x * 256 + threadIdx.x) >> 6;
  if (wid >= NN) return;
  int lane = threadIdx.x & 63;
  int p = lane >> 5, hc = lane & 31, h = hc >> 3;
  int beg = indptr[wid], end = indptr[wid + 1];
  float ad = ad1[wid*4 + h];
  float num = 0.f, den = 0.f;
  for (int j = beg + p; j < end; j += 2){
    int s = srcs[j];
    float z = as1[s*4 + h] + ad;
    z = (z >= 0.f) ? z : 0.2f * z;          // leaky_relu 0.2
    float w = __expf(z);
    num = fmaf(w, bf2f(xp1[(size_t)s*32 + hc]), num);
    den += w;
  }
  num += __shfl_xor(num, 32);
  den += __shfl_xor(den, 32);
  if (p == 0){
    float o = num / den + b1[hc];
    o = (o > 0.f) ? o : (__expf(o) - 1.f);  // ELU
    hfeat[(size_t)wid*32 + hc] = f2bf(o);
  }
}

// h[100k,32] @ W2[32,8] + attention scalars for layer 2.
__global__ void k_feat2(const u16* __restrict__ hfeat, const float* __restrict__ W2,
                        const float* __restrict__ attS, const float* __restrict__ attD,
                        float* __restrict__ xp2, float* __restrict__ as2,
                        float* __restrict__ ad2){
  int n = blockIdx.x*blockDim.x + threadIdx.x;
  if (n >= NN) return;
  const u16* hr = hfeat + (size_t)n*32;
  float h[32];
  #pragma unroll
  for (int k = 0; k < 32; k++) h[k] = bf2f(hr[k]);
  float o[8];
  #pragma unroll
  for (int j = 0; j < 8; j++) o[j] = 0.f;
  #pragma unroll
  for (int k = 0; k < 32; k++){
    #pragma unroll
    for (int j = 0; j < 8; j++) o[j] = fmaf(h[k], W2[k*8 + j], o[j]);
  }
  float s = 0.f, d = 0.f;
  #pragma unroll
  for (int j = 0; j < 8; j++){
    xp2[(size_t)n*8 + j] = o[j];
    s = fmaf(o[j], attS[j], s);
    d = fmaf(o[j], attD[j], d);
  }
  as2[n] = s; ad2[n] = d;
}

// Layer-2 aggregation: one wave per dst.
__global__ void __launch_bounds__(256) k_agg2(
    const int* __restrict__ indptr, const int* __restrict__ srcs,
    const float* __restrict__ xp2, const float* __restrict__ as2,
    const float* __restrict__ ad2, const float* __restrict__ b2,
    float* __restrict__ out){
  int wid = (blockIdx.x * 256 + threadIdx.x) >> 6;
  if (wid >= NN) return;
  int lane = threadIdx.x & 63;
  int p = lane >> 3, c = lane & 7;
  int beg = indptr[wid], end = indptr[wid + 1];
  float ad = ad2[wid];
  float num = 0.f, den = 0.f;
  for (int j = beg + p; j < end; j += 8){
    int s = srcs[j];
    float z = as2[s] + ad;
    z = (z >= 0.f) ? z : 0.2f * z;
    float w = __expf(z);
    num = fmaf(w, xp2[(size_t)s*8 + c], num);
    den += w;
  }
  num += __shfl_xor(num, 8);  den += __shfl_xor(den, 8);
  num += __shfl_xor(num, 16); den += __shfl_xor(den, 16);
  num += __shfl_xor(num, 32); den += __shfl_xor(den, 32);
  if (p == 0){
    out[(size_t)wid*8 + c] = num / den + b2[c];
  }
}

extern "C" void kernel_launch(void* const* d_in, const int* in_sizes, int n_in,
                              void* d_out, int out_size, void* d_ws, size_t ws_size,
                              hipStream_t stream){
  (void)in_sizes; (void)n_in; (void)out_size; (void)ws_size;
  const float* x   = (const float*)d_in[0];
  const int*   ei  = (const int*)d_in[1];
  const float* W1  = (const float*)d_in[2];
  const float* aS1 = (const float*)d_in[3];
  const float* aD1 = (const float*)d_in[4];
  const float* b1  = (const float*)d_in[5];
  const float* W2  = (const float*)d_in[6];
  const float* aS2 = (const float*)d_in[7];
  const float* aD2 = (const float*)d_in[8];
  const float* b2  = (const float*)d_in[9];
  float* out = (float*)d_out;

  // workspace layout (~33.7 MB), all 16B-aligned
  char* w = (char*)d_ws;
  int*   indptr = (int*)w;   w += 400016;            // N+1 ints
  int*   srcs   = (int*)w;   w += (size_t)ETOT*4;    // 13.2 MB
  u16*   xp1    = (u16*)w;   w += (size_t)NN*32*2;   // 6.4 MB  <- buk aliases here
  float* as1    = (float*)w; w += (size_t)NN*4*4;    // 1.6 MB
  float* ad1    = (float*)w; w += (size_t)NN*4*4;    // 1.6 MB
  u16*   hfeat  = (u16*)w;   w += (size_t)NN*32*2;   // 6.4 MB
  float* xp2    = (float*)w; w += (size_t)NN*8*4;
  float* as2    = (float*)w; w += (size_t)NN*4;
  float* ad2    = (float*)w; w += (size_t)NN*4;
  u16*   WTb    = (u16*)w;   w += 32*512*2;
  u32*   bcnt   = (u32*)w;   w += NBUK*4;
  u32*   bbase  = (u32*)w;   w += (NBUK+1)*4 + 12;
  u32*   gcur   = (u32*)w;   w += NBUK*4;
  // buk (13.2 MB) aliases xp1..hfeat (16 MB): dead before k_gemm1/k_agg1 write them
  u32*   buk    = (u32*)xp1;

  hipMemsetAsync(bcnt, 0, NBUK*4, stream);
  k_bcnt    <<<256, 256, 0, stream>>>(ei, bcnt);
  k_bscan   <<<1, 512, 0, stream>>>(bcnt, bbase, gcur, indptr);
  k_binA    <<<NBLK_A, 256, 0, stream>>>(ei, gcur, buk);
  k_scatterB<<<NBUK, 256, 0, stream>>>(bbase, buk, indptr, srcs);
  k_prep_w  <<<64, 256, 0, stream>>>(W1, WTb);
  k_gemm1   <<<(NN+63)/64, 256, 0, stream>>>(x, WTb, aS1, aD1, xp1, as1, ad1);
  k_agg1    <<<NN/4, 256, 0, stream>>>(indptr, srcs, xp1, as1, ad1, b1, hfeat);
  k_feat2   <<<(NN+255)/256, 256, 0, stream>>>(hfeat, W2, aS2, aD2, xp2, as2, ad2);
  k_agg2    <<<NN/4, 256, 0, stream>>>(indptr, srcs, xp2, as2, ad2, b2, out);
}

// Round 5
// 541.663 us; speedup vs baseline: 2.8715x; 1.1851x over previous
//
#include <hip/hip_runtime.h>

typedef unsigned short u16;
typedef unsigned int   u32;

#define NN  100000
#define EE  3200000
#define ETOT 3300000   // EE + NN self-loops
#define FIN 512
#define NBUK 512
#define NPB  196       // nodes per bucket; 512*196 = 100352 >= NN
#define TILE_A 8192    // edges per k_binA block
#define NBLK_A ((ETOT + TILE_A - 1) / TILE_A)   // 403

typedef __attribute__((ext_vector_type(8))) short bfx8;   // 8 bf16 (4 VGPRs)
typedef __attribute__((ext_vector_type(4))) float f32x4;  // MFMA C/D

__device__ __forceinline__ float bf2f(u16 u){ return __uint_as_float(((u32)u) << 16); }
__device__ __forceinline__ float lo16f(u32 v){ return __uint_as_float(v << 16); }
__device__ __forceinline__ float hi16f(u32 v){ return __uint_as_float(v & 0xffff0000u); }
__device__ __forceinline__ u16 f2bf(float f){
  u32 u = __float_as_uint(f);
  u += 0x7fffu + ((u >> 16) & 1u);       // round-to-nearest-even
  return (u16)(u >> 16);
}
__device__ __forceinline__ u32 pack2(float a, float b){
  return ((u32)f2bf(b) << 16) | (u32)f2bf(a);
}

// ---------- CSR build: bucketed two-pass counting sort ----------

__global__ void __launch_bounds__(256) k_bcnt(const int* __restrict__ ei,
                                              u32* __restrict__ bcnt){
  __shared__ u32 h[NBUK];
  int t = threadIdx.x;
  h[t] = 0; h[t + 256] = 0;
  __syncthreads();
  int stride = gridDim.x * 256;
  for (int e = blockIdx.x*256 + t; e < ETOT; e += stride){
    int d = (e < EE) ? ei[EE + e] : (e - EE);
    atomicAdd(&h[(u32)d / NPB], 1u);
  }
  __syncthreads();
  u32 v0 = h[t], v1 = h[t + 256];
  if (v0) atomicAdd(&bcnt[t], v0);
  if (v1) atomicAdd(&bcnt[t + 256], v1);
}

__global__ void __launch_bounds__(512) k_bscan(const u32* __restrict__ bcnt,
                                               u32* __restrict__ bbase,
                                               u32* __restrict__ gcur,
                                               int* __restrict__ indptr){
  __shared__ u32 sd[512];
  int t = threadIdx.x;
  u32 v = bcnt[t];
  sd[t] = v; __syncthreads();
  for (int o = 1; o < 512; o <<= 1){
    u32 x = (t >= o) ? sd[t - o] : 0;
    __syncthreads();
    sd[t] += x;
    __syncthreads();
  }
  u32 excl = sd[t] - v;
  bbase[t] = excl; gcur[t] = excl;
  if (t == 511) bbase[512] = sd[511];   // == ETOT
  if (t == 0)   indptr[NN] = ETOT;
}

__global__ void __launch_bounds__(256) k_binA(const int* __restrict__ ei,
                                              u32* __restrict__ gcur,
                                              u32* __restrict__ buk){
  __shared__ u32 hcnt[NBUK];
  __shared__ u32 hbase[NBUK];
  int t = threadIdx.x;
  hcnt[t] = 0; hcnt[t + 256] = 0;
  __syncthreads();
  int e0 = blockIdx.x * TILE_A;
  u32 pk[32], meta[32];
  #pragma unroll
  for (int i = 0; i < 32; i++){
    int e = e0 + i*256 + t;
    if (e < ETOT){
      int s, d;
      if (e < EE){ s = ei[e]; d = ei[EE + e]; } else { s = e - EE; d = s; }
      u32 b = (u32)d / NPB;
      pk[i] = ((u32)(d - (int)b*NPB) << 17) | (u32)s;
      u32 r = atomicAdd(&hcnt[b], 1u);
      meta[i] = (b << 13) | r;          // r < 8192
    } else meta[i] = 0xFFFFFFFFu;
  }
  __syncthreads();
  for (int q = t; q < NBUK; q += 256){
    u32 c = hcnt[q];
    if (c) hbase[q] = atomicAdd(&gcur[q], c);
  }
  __syncthreads();
  #pragma unroll
  for (int i = 0; i < 32; i++){
    if (meta[i] != 0xFFFFFFFFu){
      u32 b = meta[i] >> 13, r = meta[i] & 8191u;
      buk[hbase[b] + r] = pk[i];
    }
  }
}

__global__ void __launch_bounds__(256) k_scatterB(const u32* __restrict__ bbase,
                                                  const u32* __restrict__ buk,
                                                  int* __restrict__ indptr,
                                                  int* __restrict__ srcs){
  __shared__ u32 dcnt[NPB + 1];
  __shared__ u32 cur[NPB];
  int b = blockIdx.x, t = threadIdx.x;
  u32 lo = bbase[b], hi = bbase[b + 1];
  if (t < NPB + 1) dcnt[t] = 0;
  __syncthreads();
  for (u32 j = lo + t; j < hi; j += 256)
    atomicAdd(&dcnt[(buk[j] >> 17) + 1], 1u);
  __syncthreads();
  for (int o = 1; o < 256; o <<= 1){
    u32 x = 0;
    if (t < NPB + 1 && t >= o) x = dcnt[t - o];
    __syncthreads();
    if (t < NPB + 1 && t >= o) dcnt[t] += x;
    __syncthreads();
  }
  if (t < NPB){
    u32 off = lo + dcnt[t];
    cur[t] = off;
    int node = b * NPB + t;
    if (node < NN) indptr[node] = (int)off;
  }
  __syncthreads();
  for (u32 j = lo + t; j < hi; j += 256){
    u32 p = buk[j];
    u32 pos = atomicAdd(&cur[p >> 17], 1u);
    srcs[pos] = (int)(p & 0x1FFFFu);
  }
}

// ---------- compute kernels ----------

__global__ void k_prep_w(const float* __restrict__ W1, u16* __restrict__ WTb){
  int i = blockIdx.x*blockDim.x + threadIdx.x;   // 0..16383
  if (i >= FIN*32) return;
  int k = i >> 5, c = i & 31;
  WTb[c*FIN + k] = f2bf(W1[i]);
}

// MFMA GEMM: xp1[100k,32] = bf16(x) @ bf16(W1), f32 accumulate.
__global__ void __launch_bounds__(256) k_gemm1(
    const float* __restrict__ x, const u16* __restrict__ WTb,
    const float* __restrict__ attS, const float* __restrict__ attD,
    u16* __restrict__ xp1, float* __restrict__ as1, float* __restrict__ ad1){
  __shared__ u16 xs[64 * 136];   // 64 rows x (128 + 8 pad) bf16
  __shared__ u16 ws[32 * 520];   // 32 cols x (512 + 8 pad) bf16
  int tid = threadIdx.x;
  int nb  = blockIdx.x * 64;

  {
    int r = tid >> 3, seg = tid & 7;
    const uint4* src = (const uint4*)(WTb + r*FIN + seg*64);
    uint4* dst = (uint4*)(ws + r*520 + seg*64);
    #pragma unroll
    for (int i = 0; i < 8; i++) dst[i] = src[i];
  }

  int sr = tid >> 2, sseg = tid & 3;
  int rowc = nb + sr; if (rowc >= NN) rowc = NN - 1;
  const float* xrow = x + (size_t)rowc * FIN;

  int lane = tid & 63, wid = tid >> 6;
  int m = lane & 15, quad = lane >> 4;
  int rowbase = wid * 16;
  const u16* a_base  = xs + (rowbase + m) * 136 + quad * 8;
  const u16* b0_base = ws + m * 520 + quad * 8;
  const u16* b1_base = b0_base + 16 * 520;

  f32x4 acc0 = {0.f, 0.f, 0.f, 0.f};
  f32x4 acc1 = {0.f, 0.f, 0.f, 0.f};

  for (int kc = 0; kc < 4; kc++){
    const float4* g = (const float4*)(xrow + kc*128 + sseg*32);
    #pragma unroll
    for (int i = 0; i < 4; i++){
      float4 f0 = g[2*i], f1 = g[2*i+1];
      uint4 wv;
      wv.x = pack2(f0.x, f0.y); wv.y = pack2(f0.z, f0.w);
      wv.z = pack2(f1.x, f1.y); wv.w = pack2(f1.z, f1.w);
      *(uint4*)(xs + sr*136 + sseg*32 + i*8) = wv;
    }
    __syncthreads();
    #pragma unroll
    for (int ks = 0; ks < 4; ks++){
      bfx8 a  = *(const bfx8*)(a_base + ks*32);
      bfx8 b0 = *(const bfx8*)(b0_base + kc*128 + ks*32);
      bfx8 b1 = *(const bfx8*)(b1_base + kc*128 + ks*32);
      acc0 = __builtin_amdgcn_mfma_f32_16x16x32_bf16(a, b0, acc0, 0, 0, 0);
      acc1 = __builtin_amdgcn_mfma_f32_16x16x32_bf16(a, b1, acc1, 0, 0, 0);
    }
    __syncthreads();
  }

  #pragma unroll
  for (int t = 0; t < 2; t++){
    f32x4 acc = t ? acc1 : acc0;
    int colg = t*16 + m;
    float aS = attS[colg], aD = attD[colg];
    #pragma unroll
    for (int r = 0; r < 4; r++){
      int node = nb + rowbase + quad*4 + r;
      float v = acc[r];
      if (node < NN) xp1[(size_t)node*32 + colg] = f2bf(v);
      float ps = v * aS, pd = v * aD;
      ps += __shfl_xor(ps, 1); ps += __shfl_xor(ps, 2); ps += __shfl_xor(ps, 4);
      pd += __shfl_xor(pd, 1); pd += __shfl_xor(pd, 2); pd += __shfl_xor(pd, 4);
      if ((m & 7) == 0 && node < NN){
        as1[node*4 + (colg >> 3)] = ps;
        ad1[node*4 + (colg >> 3)] = pd;
      }
    }
  }
}

// Layer-1 aggregation: one wave per dst. Lane = (edge slot e 0..3, chanpair l 0..15).
// Each lane loads u32 = 2 bf16 channels; 4 edges + 2x unroll => 8 row-gathers in
// flight per iteration (latency hiding). Unnormalized softmax; self-loop => den>0.
__global__ void __launch_bounds__(256) k_agg1(
    const int* __restrict__ indptr, const int* __restrict__ srcs,
    const u32* __restrict__ xp1u, const float* __restrict__ as1,
    const float* __restrict__ ad1, const float* __restrict__ b1,
    u32* __restrict__ hfeatu){
  int wid = (blockIdx.x * 256 + threadIdx.x) >> 6;
  if (wid >= NN) return;
  int lane = threadIdx.x & 63;
  int e = lane >> 4;          // edge slot 0..3
  int l = lane & 15;          // channel pair: channels 2l, 2l+1
  int h = l >> 2;             // head
  int beg = indptr[wid], end = indptr[wid + 1];
  float ad = ad1[wid*4 + h];
  float num0 = 0.f, num1 = 0.f, den = 0.f;
  int j = beg + e;
  for (; j + 4 < end; j += 8){
    int s0 = srcs[j], s1 = srcs[j + 4];
    u32 v0 = xp1u[(size_t)s0*16 + l];
    u32 v1 = xp1u[(size_t)s1*16 + l];
    float z0 = as1[s0*4 + h] + ad;
    float z1 = as1[s1*4 + h] + ad;
    z0 = (z0 >= 0.f) ? z0 : 0.2f * z0;
    z1 = (z1 >= 0.f) ? z1 : 0.2f * z1;
    float w0 = __expf(z0), w1 = __expf(z1);
    num0 = fmaf(w0, lo16f(v0), num0); num1 = fmaf(w0, hi16f(v0), num1); den += w0;
    num0 = fmaf(w1, lo16f(v1), num0); num1 = fmaf(w1, hi16f(v1), num1); den += w1;
  }
  for (; j < end; j += 4){
    int s0 = srcs[j];
    u32 v0 = xp1u[(size_t)s0*16 + l];
    float z0 = as1[s0*4 + h] + ad;
    z0 = (z0 >= 0.f) ? z0 : 0.2f * z0;
    float w0 = __expf(z0);
    num0 = fmaf(w0, lo16f(v0), num0); num1 = fmaf(w0, hi16f(v0), num1); den += w0;
  }
  num0 += __shfl_xor(num0, 16); num0 += __shfl_xor(num0, 32);
  num1 += __shfl_xor(num1, 16); num1 += __shfl_xor(num1, 32);
  den  += __shfl_xor(den, 16);  den  += __shfl_xor(den, 32);
  if (e == 0){
    float o0 = num0 / den + b1[2*l];
    float o1 = num1 / den + b1[2*l + 1];
    o0 = (o0 > 0.f) ? o0 : (__expf(o0) - 1.f);   // ELU
    o1 = (o1 > 0.f) ? o1 : (__expf(o1) - 1.f);
    hfeatu[(size_t)wid*16 + l] = pack2(o0, o1);
  }
}

// h[100k,32] @ W2[32,8] + attention scalars for layer 2.
__global__ void k_feat2(const u16* __restrict__ hfeat, const float* __restrict__ W2,
                        const float* __restrict__ attS, const float* __restrict__ attD,
                        float* __restrict__ xp2, float* __restrict__ as2,
                        float* __restrict__ ad2){
  int n = blockIdx.x*blockDim.x + threadIdx.x;
  if (n >= NN) return;
  const u16* hr = hfeat + (size_t)n*32;
  float h[32];
  #pragma unroll
  for (int k = 0; k < 32; k++) h[k] = bf2f(hr[k]);
  float o[8];
  #pragma unroll
  for (int j = 0; j < 8; j++) o[j] = 0.f;
  #pragma unroll
  for (int k = 0; k < 32; k++){
    #pragma unroll
    for (int j = 0; j < 8; j++) o[j] = fmaf(h[k], W2[k*8 + j], o[j]);
  }
  float s = 0.f, d = 0.f;
  #pragma unroll
  for (int j = 0; j < 8; j++){
    xp2[(size_t)n*8 + j] = o[j];
    s = fmaf(o[j], attS[j], s);
    d = fmaf(o[j], attD[j], d);
  }
  as2[n] = s; ad2[n] = d;
}

// Layer-2 aggregation: one wave per dst, 8 edges/iter + 2x unroll.
__global__ void __launch_bounds__(256) k_agg2(
    const int* __restrict__ indptr, const int* __restrict__ srcs,
    const float* __restrict__ xp2, const float* __restrict__ as2,
    const float* __restrict__ ad2, const float* __restrict__ b2,
    float* __restrict__ out){
  int wid = (blockIdx.x * 256 + threadIdx.x) >> 6;
  if (wid >= NN) return;
  int lane = threadIdx.x & 63;
  int p = lane >> 3, c = lane & 7;
  int beg = indptr[wid], end = indptr[wid + 1];
  float ad = ad2[wid];
  float num = 0.f, den = 0.f;
  int j = beg + p;
  for (; j + 8 < end; j += 16){
    int s0 = srcs[j], s1 = srcs[j + 8];
    float v0 = xp2[(size_t)s0*8 + c];
    float v1 = xp2[(size_t)s1*8 + c];
    float z0 = as2[s0] + ad;
    float z1 = as2[s1] + ad;
    z0 = (z0 >= 0.f) ? z0 : 0.2f * z0;
    z1 = (z1 >= 0.f) ? z1 : 0.2f * z1;
    float w0 = __expf(z0), w1 = __expf(z1);
    num = fmaf(w0, v0, num); den += w0;
    num = fmaf(w1, v1, num); den += w1;
  }
  for (; j < end; j += 8){
    int s0 = srcs[j];
    float v0 = xp2[(size_t)s0*8 + c];
    float z0 = as2[s0] + ad;
    z0 = (z0 >= 0.f) ? z0 : 0.2f * z0;
    float w0 = __expf(z0);
    num = fmaf(w0, v0, num); den += w0;
  }
  num += __shfl_xor(num, 8);  den += __shfl_xor(den, 8);
  num += __shfl_xor(num, 16); den += __shfl_xor(den, 16);
  num += __shfl_xor(num, 32); den += __shfl_xor(den, 32);
  if (p == 0){
    out[(size_t)wid*8 + c] = num / den + b2[c];
  }
}

extern "C" void kernel_launch(void* const* d_in, const int* in_sizes, int n_in,
                              void* d_out, int out_size, void* d_ws, size_t ws_size,
                              hipStream_t stream){
  (void)in_sizes; (void)n_in; (void)out_size; (void)ws_size;
  const float* x   = (const float*)d_in[0];
  const int*   ei  = (const int*)d_in[1];
  const float* W1  = (const float*)d_in[2];
  const float* aS1 = (const float*)d_in[3];
  const float* aD1 = (const float*)d_in[4];
  const float* b1  = (const float*)d_in[5];
  const float* W2  = (const float*)d_in[6];
  const float* aS2 = (const float*)d_in[7];
  const float* aD2 = (const float*)d_in[8];
  const float* b2  = (const float*)d_in[9];
  float* out = (float*)d_out;

  // workspace layout (~33.7 MB), all 16B-aligned
  char* w = (char*)d_ws;
  int*   indptr = (int*)w;   w += 400016;            // N+1 ints
  int*   srcs   = (int*)w;   w += (size_t)ETOT*4;    // 13.2 MB
  u16*   xp1    = (u16*)w;   w += (size_t)NN*32*2;   // 6.4 MB  <- buk aliases here
  float* as1    = (float*)w; w += (size_t)NN*4*4;    // 1.6 MB
  float* ad1    = (float*)w; w += (size_t)NN*4*4;    // 1.6 MB
  u16*   hfeat  = (u16*)w;   w += (size_t)NN*32*2;   // 6.4 MB
  float* xp2    = (float*)w; w += (size_t)NN*8*4;
  float* as2    = (float*)w; w += (size_t)NN*4;
  float* ad2    = (float*)w; w += (size_t)NN*4;
  u16*   WTb    = (u16*)w;   w += 32*512*2;
  u32*   bcnt   = (u32*)w;   w += NBUK*4;
  u32*   bbase  = (u32*)w;   w += (NBUK+1)*4 + 12;
  u32*   gcur   = (u32*)w;   w += NBUK*4;
  // buk (13.2 MB) aliases xp1..hfeat (16 MB): dead before k_gemm1/k_agg1 write them
  u32*   buk    = (u32*)xp1;

  hipMemsetAsync(bcnt, 0, NBUK*4, stream);
  k_bcnt    <<<256, 256, 0, stream>>>(ei, bcnt);
  k_bscan   <<<1, 512, 0, stream>>>(bcnt, bbase, gcur, indptr);
  k_binA    <<<NBLK_A, 256, 0, stream>>>(ei, gcur, buk);
  k_scatterB<<<NBUK, 256, 0, stream>>>(bbase, buk, indptr, srcs);
  k_prep_w  <<<64, 256, 0, stream>>>(W1, WTb);
  k_gemm1   <<<(NN+63)/64, 256, 0, stream>>>(x, WTb, aS1, aD1, xp1, as1, ad1);
  k_agg1    <<<NN/4, 256, 0, stream>>>(indptr, srcs, (const u32*)xp1, as1, ad1, b1, (u32*)hfeat);
  k_feat2   <<<(NN+255)/256, 256, 0, stream>>>(hfeat, W2, aS2, aD2, xp2, as2, ad2);
  k_agg2    <<<NN/4, 256, 0, stream>>>(indptr, srcs, xp2, as2, ad2, b2, out);
}